// Round 1
// baseline (368.424 us; speedup 1.0000x reference)
//
#include <hip/hip_runtime.h>
#include <hip/hip_bf16.h>
#include <stdint.h>

// Problem constants (reference: B=4, S=2048, D_IN=D_K=D_V=1024)
#define B_ 4
#define S_ 2048
#define D_ 1024

typedef __attribute__((ext_vector_type(8))) short short8;   // 8 bf16 = 4 VGPRs
typedef __attribute__((ext_vector_type(4))) float floatx4;  // MFMA C/D

__device__ __forceinline__ unsigned short bf16_rne(float f) {
  union { float f; uint32_t u; } c; c.f = f;
  uint32_t u = c.u;
  return (unsigned short)((u + 0x7fffu + ((u >> 16) & 1u)) >> 16);
}

__device__ __forceinline__ void gl2lds16(const void* g, void* l) {
  // async global->LDS, 16B per lane; LDS dest is wave-uniform base + lane*16
  __builtin_amdgcn_global_load_lds(
      (const __attribute__((address_space(1))) void*)g,
      (__attribute__((address_space(3))) void*)l, 16, 0, 0);
}

// ---------------- elementwise fp32 -> bf16 cast ----------------
__global__ __launch_bounds__(256) void cast_f32_bf16(
    const float* __restrict__ in, unsigned short* __restrict__ out, int n4) {
  int i = blockIdx.x * blockDim.x + threadIdx.x;
  if (i >= n4) return;
  float4 v = ((const float4*)in)[i];
  uint32_t p0 = (uint32_t)bf16_rne(v.x) | ((uint32_t)bf16_rne(v.y) << 16);
  uint32_t p1 = (uint32_t)bf16_rne(v.z) | ((uint32_t)bf16_rne(v.w) << 16);
  ((uint2*)out)[i] = make_uint2(p0, p1);
}

// ------------- value [B,S,D] f32 -> Vt [B,D,S] bf16 (transpose-cast) -------------
__global__ __launch_bounds__(256) void cast_transpose(
    const float* __restrict__ v, unsigned short* __restrict__ vt) {
  __shared__ float tile[32][33];  // +1 pad: no bank conflicts
  const int b = blockIdx.z;
  const int d0 = blockIdx.x * 32, s0 = blockIdx.y * 32;
  const int tx = threadIdx.x, ty = threadIdx.y;  // block (32,8)
  const float* src = v + (size_t)b * S_ * D_;
#pragma unroll
  for (int i = 0; i < 4; ++i)
    tile[ty + i * 8][tx] = src[(size_t)(s0 + ty + i * 8) * D_ + d0 + tx];
  __syncthreads();
  unsigned short* dst = vt + (size_t)b * D_ * S_;
#pragma unroll
  for (int i = 0; i < 4; ++i)
    dst[(size_t)(d0 + ty + i * 8) * S_ + s0 + tx] = bf16_rne(tile[tx][ty + i * 8]);
}

// ---------------- BT-GEMM: C[m,n] = sum_k A[m,k]*B[n,k], bf16 in, fp32 accum ---------------
// m97 recipe: 128x128 tile, BK=32, 4 waves (2x2), each wave 4x4 of 16x16x32 MFMA,
// global_load_lds width-16 staging (contiguous row-major LDS tile, no padding).
// EPI 0: out bf16 = acc + bias[n];  EPI 1: out f32 = acc * scale.
template <int EPI>
__global__ __launch_bounds__(256) void gemm_bt(
    const unsigned short* __restrict__ A, const unsigned short* __restrict__ Bm,
    void* __restrict__ Cv, const float* __restrict__ bias,
    int M, int N, int K, float scale,
    long long sA, long long sB, long long sC) {
  __shared__ unsigned short smA[128 * 32];
  __shared__ unsigned short smB[128 * 32];

  const int z = blockIdx.z;
  const unsigned short* Ab = A + (size_t)z * sA;
  const unsigned short* Bb = Bm + (size_t)z * sB;

  const int tile_n = blockIdx.x * 128;
  const int tile_m = blockIdx.y * 128;

  const int t = threadIdx.x;
  const int w = t >> 6;        // wave 0..3
  const int l = t & 63;        // lane
  const int wr = w >> 1, wc = w & 1;  // 2x2 wave grid (64x64 each)

  floatx4 acc[4][4];
#pragma unroll
  for (int i = 0; i < 4; ++i)
#pragma unroll
    for (int j = 0; j < 4; ++j) acc[i][j] = (floatx4){0.f, 0.f, 0.f, 0.f};

  const int srow = l >> 2;        // staging: lane covers quarter-row (16B of 64B row)
  const int scb = (l & 3) * 16;   // byte offset within tile row
  const int kc = (l >> 4) * 8;    // fragment k-chunk (elements)
  const int rm = l & 15;          // fragment row/col within 16

  for (int kt = 0; kt < K; kt += 32) {
#pragma unroll
    for (int i = 0; i < 2; ++i) {
      const int r = (i * 4 + w) * 16 + srow;  // tile row this lane stages
      gl2lds16((const char*)Ab + ((size_t)(tile_m + r) * K + kt) * 2 + scb,
               (char*)smA + (i * 4 + w) * 1024);
      gl2lds16((const char*)Bb + ((size_t)(tile_n + r) * K + kt) * 2 + scb,
               (char*)smB + (i * 4 + w) * 1024);
    }
    __syncthreads();  // drains vmcnt -> staged tile visible

    short8 af[4], bfr[4];
#pragma unroll
    for (int i = 0; i < 4; ++i) {
      af[i]  = *(const short8*)(smA + ((wr * 64 + i * 16 + rm) * 32 + kc));
      bfr[i] = *(const short8*)(smB + ((wc * 64 + i * 16 + rm) * 32 + kc));
    }
#pragma unroll
    for (int i = 0; i < 4; ++i)
#pragma unroll
      for (int j = 0; j < 4; ++j)
        acc[i][j] = __builtin_amdgcn_mfma_f32_16x16x32_bf16(af[i], bfr[j], acc[i][j], 0, 0, 0);
    __syncthreads();  // protect LDS before next stage
  }

  // Epilogue. C/D layout: col = lane&15, row = (lane>>4)*4 + reg  [m89/m91-verified]
  const int rbase = (l >> 4) * 2;  // note: (l>>4) in 0..3 -> rows *4
#pragma unroll
  for (int i = 0; i < 4; ++i) {
#pragma unroll
    for (int j = 0; j < 4; ++j) {
      const int n = tile_n + wc * 64 + j * 16 + rm;
      const int m0 = tile_m + wr * 64 + i * 16 + (l >> 4) * 4;
      if (EPI == 0) {
        const float bv = bias[n];
        unsigned short* C = (unsigned short*)Cv + (size_t)z * sC;
#pragma unroll
        for (int r = 0; r < 4; ++r)
          C[(size_t)(m0 + r) * N + n] = bf16_rne(acc[i][j][r] + bv);
      } else {
        float* C = (float*)Cv + (size_t)z * sC;
#pragma unroll
        for (int r = 0; r < 4; ++r)
          C[(size_t)(m0 + r) * N + n] = acc[i][j][r] * scale;
      }
    }
  }
  (void)rbase; (void)M;
}

// ---------------- row softmax: fp32 logits [rows,2048] -> bf16 attn ----------------
__global__ __launch_bounds__(256) void softmax_bf16(
    const float* __restrict__ logits, unsigned short* __restrict__ attn) {
  const int row = blockIdx.x;
  const int t = threadIdx.x;
  const float* src = logits + (size_t)row * S_;
  float4 v0 = ((const float4*)src)[t * 2];
  float4 v1 = ((const float4*)src)[t * 2 + 1];
  float x[8] = {v0.x, v0.y, v0.z, v0.w, v1.x, v1.y, v1.z, v1.w};
  float m = x[0];
#pragma unroll
  for (int i = 1; i < 8; ++i) m = fmaxf(m, x[i]);
#pragma unroll
  for (int off = 32; off > 0; off >>= 1) m = fmaxf(m, __shfl_xor(m, off));
  __shared__ float sm4[4], ss4[4];
  const int wv = t >> 6, ln = t & 63;
  if (ln == 0) sm4[wv] = m;
  __syncthreads();
  m = fmaxf(fmaxf(sm4[0], sm4[1]), fmaxf(sm4[2], sm4[3]));
  float s = 0.f;
  const float LOG2E = 1.44269504088896340736f;
#pragma unroll
  for (int i = 0; i < 8; ++i) {
    x[i] = exp2f((x[i] - m) * LOG2E);
    s += x[i];
  }
#pragma unroll
  for (int off = 32; off > 0; off >>= 1) s += __shfl_xor(s, off);
  if (ln == 0) ss4[wv] = s;
  __syncthreads();
  s = ss4[0] + ss4[1] + ss4[2] + ss4[3];
  const float inv = 1.0f / s;
  uint32_t p[4];
#pragma unroll
  for (int i = 0; i < 4; ++i)
    p[i] = (uint32_t)bf16_rne(x[2 * i] * inv) |
           ((uint32_t)bf16_rne(x[2 * i + 1] * inv) << 16);
  *(uint4*)(attn + (size_t)row * S_ + t * 8) = make_uint4(p[0], p[1], p[2], p[3]);
}

extern "C" void kernel_launch(void* const* d_in, const int* in_sizes, int n_in,
                              void* d_out, int out_size, void* d_ws, size_t ws_size,
                              hipStream_t stream) {
  (void)in_sizes; (void)n_in; (void)out_size; (void)ws_size;
  const float* query  = (const float*)d_in[0];
  const float* key_in = (const float*)d_in[1];
  const float* value  = (const float*)d_in[2];
  const float* Wq     = (const float*)d_in[3];
  const float* bq     = (const float*)d_in[4];
  const float* Wk     = (const float*)d_in[5];
  const float* bk     = (const float*)d_in[6];
  // d_in[7]=Wv, d_in[8]=bv: unused by the reference math (original model quirk).
  float* out = (float*)d_out;

  // Workspace layout (180 MiB total; every byte written before read each call)
  char* ws = (char*)d_ws;
  const size_t MiB = 1024 * 1024;
  unsigned short* Xq  = (unsigned short*)(ws);              // 16 MiB  query bf16
  unsigned short* Xk  = (unsigned short*)(ws + 16 * MiB);   // 16 MiB  key_in bf16
  unsigned short* Wqb = (unsigned short*)(ws + 32 * MiB);   //  2 MiB  Wq bf16
  unsigned short* Wkb = (unsigned short*)(ws + 34 * MiB);   //  2 MiB  Wk bf16
  unsigned short* Vt  = (unsigned short*)(ws + 36 * MiB);   // 16 MiB  value^T bf16 [B,D,S]
  unsigned short* Qp  = (unsigned short*)(ws + 52 * MiB);   // 16 MiB  Q bf16
  unsigned short* Kp  = (unsigned short*)(ws + 68 * MiB);   // 16 MiB  K bf16
  float*          Lg  = (float*)(ws + 84 * MiB);            // 64 MiB  logits f32
  unsigned short* At  = (unsigned short*)(ws + 148 * MiB);  // 32 MiB  attn bf16

  const int nXD4 = B_ * S_ * D_ / 4;   // 2097152
  const int nW4  = D_ * D_ / 4;        // 262144
  cast_f32_bf16<<<(nXD4 + 255) / 256, 256, 0, stream>>>(query, Xq, nXD4);
  cast_f32_bf16<<<(nXD4 + 255) / 256, 256, 0, stream>>>(key_in, Xk, nXD4);
  cast_f32_bf16<<<(nW4 + 255) / 256, 256, 0, stream>>>(Wq, Wqb, nW4);
  cast_f32_bf16<<<(nW4 + 255) / 256, 256, 0, stream>>>(Wk, Wkb, nW4);
  cast_transpose<<<dim3(D_ / 32, S_ / 32, B_), dim3(32, 8), 0, stream>>>(value, Vt);

  // Q = query@Wq^T + bq ; K = key_in@Wk^T + bk   (M=8192, N=1024, K=1024)
  gemm_bt<0><<<dim3(D_ / 128, B_ * S_ / 128, 1), 256, 0, stream>>>(
      Xq, Wqb, Qp, bq, B_ * S_, D_, D_, 0.f, 0, 0, 0);
  gemm_bt<0><<<dim3(D_ / 128, B_ * S_ / 128, 1), 256, 0, stream>>>(
      Xk, Wkb, Kp, bk, B_ * S_, D_, D_, 0.f, 0, 0, 0);

  // logits = Q@K^T * D^-0.5 per batch (M=N=2048, K=1024)
  gemm_bt<1><<<dim3(S_ / 128, S_ / 128, B_), 256, 0, stream>>>(
      Qp, Kp, Lg, nullptr, S_, S_, D_, 0.03125f,
      (long long)S_ * D_, (long long)S_ * D_, (long long)S_ * S_);

  // attn = softmax(logits) rowwise -> bf16
  softmax_bf16<<<B_ * S_, 256, 0, stream>>>(Lg, At);

  // out = attn @ value  == BT-GEMM vs Vt (M=2048, N=1024, K=2048) per batch
  gemm_bt<1><<<dim3(D_ / 128, S_ / 128, B_), 256, 0, stream>>>(
      At, Vt, out, nullptr, S_, D_, S_, 1.0f,
      (long long)S_ * S_, (long long)D_ * S_, (long long)S_ * D_);
}

// Round 2
// 315.770 us; speedup vs baseline: 1.1667x; 1.1667x over previous
//
#include <hip/hip_runtime.h>
#include <hip/hip_bf16.h>
#include <stdint.h>

// Problem constants (reference: B=4, S=2048, D_IN=D_K=D_V=1024)
#define B_ 4
#define S_ 2048
#define D_ 1024

typedef __attribute__((ext_vector_type(8))) short short8;   // 8 bf16 = 4 VGPRs
typedef __attribute__((ext_vector_type(4))) float floatx4;  // MFMA C/D

__device__ __forceinline__ unsigned short bf16_rne(float f) {
  union { float f; uint32_t u; } c; c.f = f;
  uint32_t u = c.u;
  return (unsigned short)((u + 0x7fffu + ((u >> 16) & 1u)) >> 16);
}

__device__ __forceinline__ float bf16_to_f32(unsigned short h) {
  union { uint32_t u; float f; } c; c.u = ((uint32_t)h) << 16;
  return c.f;
}

__device__ __forceinline__ void gl2lds16(const void* g, void* l) {
  // async global->LDS, 16B per lane; LDS dest is wave-uniform base + lane*16
  __builtin_amdgcn_global_load_lds(
      (const __attribute__((address_space(1))) void*)g,
      (__attribute__((address_space(3))) void*)l, 16, 0, 0);
}

// ------- fused cast: query,key_in,Wq,Wk f32->bf16 + biases packed f32 -------
// hardcoded float4 segment offsets: query 2097152, key 2097152, Wq 262144,
// Wk 262144, then bq 256 + bk 256 float4 copies into contiguous Bias buffer.
__global__ __launch_bounds__(256) void cast_all(
    const float* __restrict__ q, const float* __restrict__ k,
    const float* __restrict__ wq, const float* __restrict__ wk,
    const float* __restrict__ bq, const float* __restrict__ bk,
    unsigned short* __restrict__ oq, unsigned short* __restrict__ ok,
    unsigned short* __restrict__ owq, unsigned short* __restrict__ owk,
    float* __restrict__ bias) {
  int i = blockIdx.x * 256 + threadIdx.x;
  if (i < 4718592) {
    const float* src; unsigned short* dst; int off;
    if (i < 2097152)      { src = q;  dst = oq;  off = i; }
    else if (i < 4194304) { src = k;  dst = ok;  off = i - 2097152; }
    else if (i < 4456448) { src = wq; dst = owq; off = i - 4194304; }
    else                  { src = wk; dst = owk; off = i - 4456448; }
    float4 v = ((const float4*)src)[off];
    uint32_t p0 = (uint32_t)bf16_rne(v.x) | ((uint32_t)bf16_rne(v.y) << 16);
    uint32_t p1 = (uint32_t)bf16_rne(v.z) | ((uint32_t)bf16_rne(v.w) << 16);
    ((uint2*)dst)[off] = make_uint2(p0, p1);
  } else {
    int j = i - 4718592;  // 0..511: bias copy (f32 -> f32, packed)
    const float* src = (j < 256) ? bq : bk;
    int off = j & 255;
    ((float4*)bias)[j] = ((const float4*)src)[off];
  }
}

// ------------- value [B,S,D] f32 -> Vt [B,D,S] bf16 (transpose-cast) -------------
__global__ __launch_bounds__(256) void cast_transpose(
    const float* __restrict__ v, unsigned short* __restrict__ vt) {
  __shared__ float tile[32][33];  // +1 pad: no bank conflicts
  const int b = blockIdx.z;
  const int d0 = blockIdx.x * 32, s0 = blockIdx.y * 32;
  const int tx = threadIdx.x, ty = threadIdx.y;  // block (32,8)
  const float* src = v + (size_t)b * S_ * D_;
#pragma unroll
  for (int i = 0; i < 4; ++i)
    tile[ty + i * 8][tx] = src[(size_t)(s0 + ty + i * 8) * D_ + d0 + tx];
  __syncthreads();
  unsigned short* dst = vt + (size_t)b * D_ * S_;
#pragma unroll
  for (int i = 0; i < 4; ++i)
    dst[(size_t)(d0 + ty + i * 8) * S_ + s0 + tx] = bf16_rne(tile[tx][ty + i * 8]);
}

// ---------------- BT-GEMM: C[m,n] = sum_k A[m,k]*B[n,k], bf16 in, fp32 accum ---------------
// 128x128 tile, TWO BK=32 steps per barrier pair (2-buffer LDS, 32KB) to halve
// the per-iter s_waitcnt vmcnt(0)+s_barrier drain. 4 waves (2x2), wave 64x64 via
// 4x4 of 16x16x32 MFMA. global_load_lds width-16 staging.
// EPI 0: bf16 = acc + bias[n]; EPI 1: f32 = acc*scale; EPI 2: bf16 = acc*scale.
template <int EPI>
__global__ __launch_bounds__(256) void gemm_bt(
    const unsigned short* __restrict__ A, const unsigned short* __restrict__ Bm,
    void* __restrict__ Cv, const float* __restrict__ bias,
    int M, int N, int K, float scale,
    long long sA, long long sB, long long sC, long long sBias) {
  __shared__ unsigned short smA[2][128 * 32];
  __shared__ unsigned short smB[2][128 * 32];

  const int z = blockIdx.z;
  const unsigned short* Ab = A + (size_t)z * sA;
  const unsigned short* Bb = Bm + (size_t)z * sB;

  const int tile_n = blockIdx.x * 128;
  const int tile_m = blockIdx.y * 128;

  const int t = threadIdx.x;
  const int w = t >> 6;        // wave 0..3
  const int l = t & 63;        // lane
  const int wr = w >> 1, wc = w & 1;  // 2x2 wave grid (64x64 each)

  floatx4 acc[4][4];
#pragma unroll
  for (int i = 0; i < 4; ++i)
#pragma unroll
    for (int j = 0; j < 4; ++j) acc[i][j] = (floatx4){0.f, 0.f, 0.f, 0.f};

  const int srow = l >> 2;        // staging: lane covers quarter-row (16B of 64B row)
  const int scb = (l & 3) * 16;   // byte offset within tile row
  const int kc = (l >> 4) * 8;    // fragment k-chunk (elements)
  const int rm = l & 15;          // fragment row/col within 16

  for (int kt = 0; kt < K; kt += 64) {
#pragma unroll
    for (int h = 0; h < 2; ++h) {
#pragma unroll
      for (int i = 0; i < 2; ++i) {
        const int r = (i * 4 + w) * 16 + srow;  // tile row this lane stages
        gl2lds16((const char*)Ab + ((size_t)(tile_m + r) * K + kt + h * 32) * 2 + scb,
                 (char*)smA[h] + (i * 4 + w) * 1024);
        gl2lds16((const char*)Bb + ((size_t)(tile_n + r) * K + kt + h * 32) * 2 + scb,
                 (char*)smB[h] + (i * 4 + w) * 1024);
      }
    }
    __syncthreads();  // drains vmcnt -> both staged tiles visible

#pragma unroll
    for (int h = 0; h < 2; ++h) {
      short8 af[4], bfr[4];
#pragma unroll
      for (int i = 0; i < 4; ++i) {
        af[i]  = *(const short8*)(smA[h] + ((wr * 64 + i * 16 + rm) * 32 + kc));
        bfr[i] = *(const short8*)(smB[h] + ((wc * 64 + i * 16 + rm) * 32 + kc));
      }
#pragma unroll
      for (int i = 0; i < 4; ++i)
#pragma unroll
        for (int j = 0; j < 4; ++j)
          acc[i][j] = __builtin_amdgcn_mfma_f32_16x16x32_bf16(af[i], bfr[j], acc[i][j], 0, 0, 0);
    }
    __syncthreads();  // protect LDS before next stage
  }

  // Epilogue. C/D layout: col = lane&15, row = (lane>>4)*4 + reg  [m89/m91-verified]
#pragma unroll
  for (int i = 0; i < 4; ++i) {
#pragma unroll
    for (int j = 0; j < 4; ++j) {
      const int n = tile_n + wc * 64 + j * 16 + rm;
      const int m0 = tile_m + wr * 64 + i * 16 + (l >> 4) * 4;
      if (EPI == 0) {
        const float bv = bias[(size_t)z * sBias + n];
        unsigned short* C = (unsigned short*)Cv + (size_t)z * sC;
#pragma unroll
        for (int r = 0; r < 4; ++r)
          C[(size_t)(m0 + r) * N + n] = bf16_rne(acc[i][j][r] + bv);
      } else if (EPI == 1) {
        float* C = (float*)Cv + (size_t)z * sC;
#pragma unroll
        for (int r = 0; r < 4; ++r)
          C[(size_t)(m0 + r) * N + n] = acc[i][j][r] * scale;
      } else {
        unsigned short* C = (unsigned short*)Cv + (size_t)z * sC;
#pragma unroll
        for (int r = 0; r < 4; ++r)
          C[(size_t)(m0 + r) * N + n] = bf16_rne(acc[i][j][r] * scale);
      }
    }
  }
  (void)M;
}

// ---------------- row softmax: bf16 logits [rows,2048] -> bf16 attn ----------------
__global__ __launch_bounds__(256) void softmax_bf16(
    const unsigned short* __restrict__ logits, unsigned short* __restrict__ attn) {
  const int row = blockIdx.x;
  const int t = threadIdx.x;
  uint4 raw = *(const uint4*)(logits + (size_t)row * S_ + t * 8);
  float x[8];
  const uint32_t ru[4] = {raw.x, raw.y, raw.z, raw.w};
#pragma unroll
  for (int i = 0; i < 4; ++i) {
    union { uint32_t u; float f; } lo, hi;
    lo.u = ru[i] << 16;
    hi.u = ru[i] & 0xffff0000u;
    x[2 * i] = lo.f;
    x[2 * i + 1] = hi.f;
  }
  float m = x[0];
#pragma unroll
  for (int i = 1; i < 8; ++i) m = fmaxf(m, x[i]);
#pragma unroll
  for (int off = 32; off > 0; off >>= 1) m = fmaxf(m, __shfl_xor(m, off));
  __shared__ float sm4[4], ss4[4];
  const int wv = t >> 6, ln = t & 63;
  if (ln == 0) sm4[wv] = m;
  __syncthreads();
  m = fmaxf(fmaxf(sm4[0], sm4[1]), fmaxf(sm4[2], sm4[3]));
  float s = 0.f;
  const float LOG2E = 1.44269504088896340736f;
#pragma unroll
  for (int i = 0; i < 8; ++i) {
    x[i] = exp2f((x[i] - m) * LOG2E);
    s += x[i];
  }
#pragma unroll
  for (int off = 32; off > 0; off >>= 1) s += __shfl_xor(s, off);
  if (ln == 0) ss4[wv] = s;
  __syncthreads();
  s = ss4[0] + ss4[1] + ss4[2] + ss4[3];
  const float inv = 1.0f / s;
  uint32_t p[4];
#pragma unroll
  for (int i = 0; i < 4; ++i)
    p[i] = (uint32_t)bf16_rne(x[2 * i] * inv) |
           ((uint32_t)bf16_rne(x[2 * i + 1] * inv) << 16);
  *(uint4*)(attn + (size_t)row * S_ + t * 8) = make_uint4(p[0], p[1], p[2], p[3]);
}

extern "C" void kernel_launch(void* const* d_in, const int* in_sizes, int n_in,
                              void* d_out, int out_size, void* d_ws, size_t ws_size,
                              hipStream_t stream) {
  (void)in_sizes; (void)n_in; (void)out_size; (void)ws_size;
  const float* query  = (const float*)d_in[0];
  const float* key_in = (const float*)d_in[1];
  const float* value  = (const float*)d_in[2];
  const float* Wq     = (const float*)d_in[3];
  const float* bq     = (const float*)d_in[4];
  const float* Wk     = (const float*)d_in[5];
  const float* bk     = (const float*)d_in[6];
  // d_in[7]=Wv, d_in[8]=bv: unused by the reference math (original model quirk).
  float* out = (float*)d_out;

  // Workspace layout (149 MiB used; every byte written before read each call)
  char* ws = (char*)d_ws;
  const size_t MiB = 1024 * 1024;
  unsigned short* Xq  = (unsigned short*)(ws);              // 16 MiB  query bf16
  unsigned short* Xk  = (unsigned short*)(ws + 16 * MiB);   // 16 MiB  key_in bf16 (contiguous after Xq)
  unsigned short* Wqb = (unsigned short*)(ws + 32 * MiB);   //  2 MiB  Wq bf16
  unsigned short* Wkb = (unsigned short*)(ws + 34 * MiB);   //  2 MiB  Wk bf16 (contiguous after Wqb)
  float*          Bias= (float*)(ws + 36 * MiB);            //  8 KiB  [bq | bk] packed
  unsigned short* Vt  = (unsigned short*)(ws + 37 * MiB);   // 16 MiB  value^T bf16 [B,D,S]
  unsigned short* Qp  = (unsigned short*)(ws + 53 * MiB);   // 16 MiB  Q bf16
  unsigned short* Kp  = (unsigned short*)(ws + 69 * MiB);   // 16 MiB  K bf16 (contiguous after Qp)
  unsigned short* Lg  = (unsigned short*)(ws + 85 * MiB);   // 32 MiB  logits bf16
  unsigned short* At  = (unsigned short*)(ws + 117 * MiB);  // 32 MiB  attn bf16

  // 1) all elementwise casts + bias packing in one dispatch
  cast_all<<<18434, 256, 0, stream>>>(query, key_in, Wq, Wk, bq, bk,
                                      Xq, Xk, Wqb, Wkb, Bias);
  // 2) transpose-cast value
  cast_transpose<<<dim3(D_ / 32, S_ / 32, B_), dim3(32, 8), 0, stream>>>(value, Vt);

  // 3) Q & K projections fused via z: z=0 -> Q=query@Wq^T+bq, z=1 -> K=key_in@Wk^T+bk
  //    (Xq/Xk, Wqb/Wkb, Qp/Kp, bq/bk all contiguous -> pure stride batching)
  gemm_bt<0><<<dim3(D_ / 128, B_ * S_ / 128, 2), 256, 0, stream>>>(
      Xq, Wqb, Qp, Bias, B_ * S_, D_, D_, 0.f,
      (long long)B_ * S_ * D_, (long long)D_ * D_, (long long)B_ * S_ * D_, D_);

  // 4) logits = Q@K^T * D^-0.5 per batch -> bf16 (M=N=2048, K=1024)
  gemm_bt<2><<<dim3(S_ / 128, S_ / 128, B_), 256, 0, stream>>>(
      Qp, Kp, Lg, nullptr, S_, S_, D_, 0.03125f,
      (long long)S_ * D_, (long long)S_ * D_, (long long)S_ * S_, 0);

  // 5) attn = softmax(logits) rowwise -> bf16
  softmax_bf16<<<B_ * S_, 256, 0, stream>>>(Lg, At);

  // 6) out = attn @ value == BT-GEMM vs Vt (M=2048, N=1024, K=2048) per batch
  gemm_bt<1><<<dim3(D_ / 128, S_ / 128, B_), 256, 0, stream>>>(
      At, Vt, out, nullptr, S_, D_, S_, 1.0f,
      (long long)S_ * S_, (long long)D_ * S_, (long long)S_ * D_, 0);
}

// Round 3
// 304.610 us; speedup vs baseline: 1.2095x; 1.0366x over previous
//
#include <hip/hip_runtime.h>
#include <hip/hip_bf16.h>
#include <stdint.h>

// Problem constants (reference: B=4, S=2048, D_IN=D_K=D_V=1024)
#define B_ 4
#define S_ 2048
#define D_ 1024

typedef __attribute__((ext_vector_type(8))) short short8;   // 8 bf16 = 4 VGPRs
typedef __attribute__((ext_vector_type(4))) float floatx4;  // MFMA C/D

__device__ __forceinline__ unsigned short bf16_rne(float f) {
  union { float f; uint32_t u; } c; c.f = f;
  uint32_t u = c.u;
  return (unsigned short)((u + 0x7fffu + ((u >> 16) & 1u)) >> 16);
}

__device__ __forceinline__ void gl2lds16(const void* g, void* l) {
  // async global->LDS, 16B per lane; LDS dest is wave-uniform base + lane*16
  __builtin_amdgcn_global_load_lds(
      (const __attribute__((address_space(1))) void*)g,
      (__attribute__((address_space(3))) void*)l, 16, 0, 0);
}

// ---- merged prep: casts of query/key/Wq/Wk, bias packing, value transpose ----
// blocks [0, 18432): float4 casts; [18432, 18434): bias pack;
// [18434, 26626): 32x32 transpose-cast tiles of value.
__global__ __launch_bounds__(256) void prep_all(
    const float* __restrict__ q, const float* __restrict__ k,
    const float* __restrict__ wq, const float* __restrict__ wk,
    const float* __restrict__ bq, const float* __restrict__ bk,
    const float* __restrict__ v,
    unsigned short* __restrict__ oq, unsigned short* __restrict__ ok,
    unsigned short* __restrict__ owq, unsigned short* __restrict__ owk,
    float* __restrict__ bias, unsigned short* __restrict__ vt) {
  __shared__ float tile[32][33];
  const int blk = blockIdx.x;
  if (blk < 18432) {
    int i = blk * 256 + threadIdx.x;
    const float* src; unsigned short* dst; int off;
    if (i < 2097152)      { src = q;  dst = oq;  off = i; }
    else if (i < 4194304) { src = k;  dst = ok;  off = i - 2097152; }
    else if (i < 4456448) { src = wq; dst = owq; off = i - 4194304; }
    else                  { src = wk; dst = owk; off = i - 4456448; }
    float4 vv = ((const float4*)src)[off];
    uint32_t p0 = (uint32_t)bf16_rne(vv.x) | ((uint32_t)bf16_rne(vv.y) << 16);
    uint32_t p1 = (uint32_t)bf16_rne(vv.z) | ((uint32_t)bf16_rne(vv.w) << 16);
    ((uint2*)dst)[off] = make_uint2(p0, p1);
  } else if (blk < 18434) {
    int j = (blk - 18432) * 256 + threadIdx.x;  // 0..511
    const float* src = (j < 256) ? bq : bk;
    ((float4*)bias)[j] = ((const float4*)src)[j & 255];
  } else {
    const int bi = blk - 18434;
    const int d0 = (bi & 31) * 32;          // D/32 = 32
    const int s0 = ((bi >> 5) & 63) * 32;   // S/32 = 64
    const int b  = bi >> 11;                // B = 4
    const int tx = threadIdx.x & 31, ty = threadIdx.x >> 5;  // (32,8)
    const float* src = v + (size_t)b * S_ * D_;
#pragma unroll
    for (int i = 0; i < 4; ++i)
      tile[ty + i * 8][tx] = src[(size_t)(s0 + ty + i * 8) * D_ + d0 + tx];
    __syncthreads();
    unsigned short* dst = vt + (size_t)b * D_ * S_;
#pragma unroll
    for (int i = 0; i < 4; ++i)
      dst[(size_t)(d0 + ty + i * 8) * S_ + s0 + tx] = bf16_rne(tile[tx][ty + i * 8]);
  }
}

// ---------------- BT-GEMM: C[m,n] = sum_k A[m,k]*B[n,k], bf16 in, fp32 accum ---------------
// Block tile BM x 128, 4 waves (2x2), wave tile (BM/2) x 64 as (BM/32) x 4 of
// 16x16x32 MFMAs. TWO BK=32 stages per barrier pair. BM=256: LDS bytes/MAC
// 0.0458 vs 0.0625 at BM=128 (LDS-BW-bound regime -> higher MfmaUtil).
// EPI 0: bf16 = acc + bias[n]; EPI 1: f32 = acc*scale; EPI 2: bf16 = acc*scale.
template <int EPI, int BM>
__global__ __launch_bounds__(256, BM == 128 ? 3 : 2) void gemm_bt(
    const unsigned short* __restrict__ A, const unsigned short* __restrict__ Bm,
    void* __restrict__ Cv, const float* __restrict__ bias,
    int N, int K, float scale,
    long long sA, long long sB, long long sC, long long sBias) {
  constexpr int IC = BM / 32;    // A-frags per wave (m direction)
  constexpr int AST = BM / 64;   // A staging instrs per thread per k32
  __shared__ unsigned short smA[2][BM * 32];
  __shared__ unsigned short smB[2][128 * 32];

  const int z = blockIdx.z;
  const unsigned short* Ab = A + (size_t)z * sA;
  const unsigned short* Bb = Bm + (size_t)z * sB;

  const int tile_n = blockIdx.x * 128;
  const int tile_m = blockIdx.y * BM;

  const int t = threadIdx.x;
  const int w = t >> 6;        // wave 0..3
  const int l = t & 63;        // lane
  const int wr = w >> 1, wc = w & 1;  // 2x2 wave grid

  floatx4 acc[IC][4];
#pragma unroll
  for (int i = 0; i < IC; ++i)
#pragma unroll
    for (int j = 0; j < 4; ++j) acc[i][j] = (floatx4){0.f, 0.f, 0.f, 0.f};

  const int srow = l >> 2;        // staging: lane covers quarter-row (16B of 64B row)
  const int scb = (l & 3) * 16;   // byte offset within tile row
  const int kc = (l >> 4) * 8;    // fragment k-chunk (elements)
  const int rm = l & 15;          // fragment row/col within 16

  for (int kt = 0; kt < K; kt += 64) {
#pragma unroll
    for (int h = 0; h < 2; ++h) {
#pragma unroll
      for (int i = 0; i < AST; ++i) {
        const int r = (i * 4 + w) * 16 + srow;
        gl2lds16((const char*)Ab + ((size_t)(tile_m + r) * K + kt + h * 32) * 2 + scb,
                 (char*)smA[h] + (i * 4 + w) * 1024);
      }
#pragma unroll
      for (int i = 0; i < 2; ++i) {
        const int r = (i * 4 + w) * 16 + srow;
        gl2lds16((const char*)Bb + ((size_t)(tile_n + r) * K + kt + h * 32) * 2 + scb,
                 (char*)smB[h] + (i * 4 + w) * 1024);
      }
    }
    __syncthreads();  // drains vmcnt -> both staged tiles visible

#pragma unroll
    for (int h = 0; h < 2; ++h) {
      short8 bfr[4];
#pragma unroll
      for (int j = 0; j < 4; ++j)
        bfr[j] = *(const short8*)(smB[h] + ((wc * 64 + j * 16 + rm) * 32 + kc));
#pragma unroll
      for (int i = 0; i < IC; ++i) {
        const short8 af = *(const short8*)(smA[h] + ((wr * (BM / 2) + i * 16 + rm) * 32 + kc));
#pragma unroll
        for (int j = 0; j < 4; ++j)
          acc[i][j] = __builtin_amdgcn_mfma_f32_16x16x32_bf16(af, bfr[j], acc[i][j], 0, 0, 0);
      }
    }
    __syncthreads();  // protect LDS before next stage
  }

  // Epilogue. C/D layout: col = lane&15, row = (lane>>4)*4 + reg  [m89/m91-verified]
#pragma unroll
  for (int i = 0; i < IC; ++i) {
#pragma unroll
    for (int j = 0; j < 4; ++j) {
      const int n = tile_n + wc * 64 + j * 16 + rm;
      const int m0 = tile_m + wr * (BM / 2) + i * 16 + (l >> 4) * 4;
      if (EPI == 0) {
        const float bv = bias[(size_t)z * sBias + n];
        unsigned short* C = (unsigned short*)Cv + (size_t)z * sC;
#pragma unroll
        for (int r = 0; r < 4; ++r)
          C[(size_t)(m0 + r) * N + n] = bf16_rne(acc[i][j][r] + bv);
      } else if (EPI == 1) {
        float* C = (float*)Cv + (size_t)z * sC;
#pragma unroll
        for (int r = 0; r < 4; ++r)
          C[(size_t)(m0 + r) * N + n] = acc[i][j][r] * scale;
      } else {
        unsigned short* C = (unsigned short*)Cv + (size_t)z * sC;
#pragma unroll
        for (int r = 0; r < 4; ++r)
          C[(size_t)(m0 + r) * N + n] = bf16_rne(acc[i][j][r] * scale);
      }
    }
  }
}

// ---------------- row softmax: bf16 logits [rows,2048] -> bf16 attn ----------------
__global__ __launch_bounds__(256) void softmax_bf16(
    const unsigned short* __restrict__ logits, unsigned short* __restrict__ attn) {
  const int row = blockIdx.x;
  const int t = threadIdx.x;
  uint4 raw = *(const uint4*)(logits + (size_t)row * S_ + t * 8);
  float x[8];
  const uint32_t ru[4] = {raw.x, raw.y, raw.z, raw.w};
#pragma unroll
  for (int i = 0; i < 4; ++i) {
    union { uint32_t u; float f; } lo, hi;
    lo.u = ru[i] << 16;
    hi.u = ru[i] & 0xffff0000u;
    x[2 * i] = lo.f;
    x[2 * i + 1] = hi.f;
  }
  float m = x[0];
#pragma unroll
  for (int i = 1; i < 8; ++i) m = fmaxf(m, x[i]);
#pragma unroll
  for (int off = 32; off > 0; off >>= 1) m = fmaxf(m, __shfl_xor(m, off));
  __shared__ float sm4[4], ss4[4];
  const int wv = t >> 6, ln = t & 63;
  if (ln == 0) sm4[wv] = m;
  __syncthreads();
  m = fmaxf(fmaxf(sm4[0], sm4[1]), fmaxf(sm4[2], sm4[3]));
  float s = 0.f;
  const float LOG2E = 1.44269504088896340736f;
#pragma unroll
  for (int i = 0; i < 8; ++i) {
    x[i] = exp2f((x[i] - m) * LOG2E);
    s += x[i];
  }
#pragma unroll
  for (int off = 32; off > 0; off >>= 1) s += __shfl_xor(s, off);
  if (ln == 0) ss4[wv] = s;
  __syncthreads();
  s = ss4[0] + ss4[1] + ss4[2] + ss4[3];
  const float inv = 1.0f / s;
  uint32_t p[4];
#pragma unroll
  for (int i = 0; i < 4; ++i)
    p[i] = (uint32_t)bf16_rne(x[2 * i] * inv) |
           ((uint32_t)bf16_rne(x[2 * i + 1] * inv) << 16);
  *(uint4*)(attn + (size_t)row * S_ + t * 8) = make_uint4(p[0], p[1], p[2], p[3]);
}

extern "C" void kernel_launch(void* const* d_in, const int* in_sizes, int n_in,
                              void* d_out, int out_size, void* d_ws, size_t ws_size,
                              hipStream_t stream) {
  (void)in_sizes; (void)n_in; (void)out_size; (void)ws_size;
  const float* query  = (const float*)d_in[0];
  const float* key_in = (const float*)d_in[1];
  const float* value  = (const float*)d_in[2];
  const float* Wq     = (const float*)d_in[3];
  const float* bq     = (const float*)d_in[4];
  const float* Wk     = (const float*)d_in[5];
  const float* bk     = (const float*)d_in[6];
  // d_in[7]=Wv, d_in[8]=bv: unused by the reference math (original model quirk).
  float* out = (float*)d_out;

  // Workspace layout (149 MiB used; every byte written before read each call)
  char* ws = (char*)d_ws;
  const size_t MiB = 1024 * 1024;
  unsigned short* Xq  = (unsigned short*)(ws);              // 16 MiB  query bf16
  unsigned short* Xk  = (unsigned short*)(ws + 16 * MiB);   // 16 MiB  key_in bf16 (contiguous after Xq)
  unsigned short* Wqb = (unsigned short*)(ws + 32 * MiB);   //  2 MiB  Wq bf16
  unsigned short* Wkb = (unsigned short*)(ws + 34 * MiB);   //  2 MiB  Wk bf16 (contiguous after Wqb)
  float*          Bias= (float*)(ws + 36 * MiB);            //  8 KiB  [bq | bk] packed
  unsigned short* Vt  = (unsigned short*)(ws + 37 * MiB);   // 16 MiB  value^T bf16 [B,D,S]
  unsigned short* Qp  = (unsigned short*)(ws + 53 * MiB);   // 16 MiB  Q bf16
  unsigned short* Kp  = (unsigned short*)(ws + 69 * MiB);   // 16 MiB  K bf16 (contiguous after Qp)
  unsigned short* Lg  = (unsigned short*)(ws + 85 * MiB);   // 32 MiB  logits bf16
  unsigned short* At  = (unsigned short*)(ws + 117 * MiB);  // 32 MiB  attn bf16

  // 1) all casts + bias pack + value transpose in one dispatch
  prep_all<<<26626, 256, 0, stream>>>(query, key_in, Wq, Wk, bq, bk, value,
                                      Xq, Xk, Wqb, Wkb, Bias, Vt);

  // 2) Q & K projections fused via z (BM=256: M=8192 -> 32 m-tiles, grid 512)
  gemm_bt<0, 256><<<dim3(D_ / 128, B_ * S_ / 256, 2), 256, 0, stream>>>(
      Xq, Wqb, Qp, Bias, D_, D_, 0.f,
      (long long)B_ * S_ * D_, (long long)D_ * D_, (long long)B_ * S_ * D_, D_);

  // 3) logits = Q@K^T * D^-0.5 per batch -> bf16 (BM=256: grid 16x8x4 = 512)
  gemm_bt<2, 256><<<dim3(S_ / 128, S_ / 256, B_), 256, 0, stream>>>(
      Qp, Kp, Lg, nullptr, S_, D_, 0.03125f,
      (long long)S_ * D_, (long long)S_ * D_, (long long)S_ * S_, 0);

  // 4) attn = softmax(logits) rowwise -> bf16
  softmax_bf16<<<B_ * S_, 256, 0, stream>>>(Lg, At);

  // 5) out = attn @ value == BT-GEMM vs Vt (BM=128 keeps grid 512 = 2 blocks/CU)
  gemm_bt<1, 128><<<dim3(D_ / 128, S_ / 128, B_), 256, 0, stream>>>(
      At, Vt, out, nullptr, D_, S_, 1.0f,
      (long long)S_ * S_, (long long)D_ * S_, (long long)S_ * D_, 0);
}